// Round 5
// baseline (213.773 us; speedup 1.0000x reference)
//
#include <hip/hip_runtime.h>

// GCN forward, f32, CSR-gather; W1 register-resident, ILP-4 chains, xs precompute.
// Pipeline:
//  M  memsetAsync: zero cnt_out/cnt_in
//  K1 edge histogram (int atomics)
//  K2 per-block exclusive scan of cnt_in -> cursor(partial) + bsum
//  K3 single-block exclusive scan of bsum
//  K4 finalize+xs: cursor += bsum-prefix; norms; xs[i][d] = norm_src[i]*x[i][d]
//  K5 bin edges by dst (cursor -> end offsets)
//  K6 fused per-node (1 wave/node, grid-stride): gather xs + reg-MLP -> zs
//  K7 layer-2 gather (8 lanes/node) -> out
// zs overlays cnt_out (dead after K4).

constexpr int D = 64;

__device__ __forceinline__ int rl_i(int v, int l) {
    return __builtin_amdgcn_readlane(v, l);
}
__device__ __forceinline__ float rl_f(float v, int l) {
    return __builtin_bit_cast(float, __builtin_amdgcn_readlane(__builtin_bit_cast(int, v), l));
}

__global__ void k_hist(const int* __restrict__ src, const int* __restrict__ dst,
                       int* __restrict__ cnt_out, int* __restrict__ cnt_in, int e) {
    int i = blockIdx.x * blockDim.x + threadIdx.x;
    if (i < e) {
        atomicAdd(&cnt_out[src[i]], 1);
        atomicAdd(&cnt_in[dst[i]], 1);
    }
}

__global__ void k_scan_block(const int* __restrict__ cnt_in, int* __restrict__ cursor,
                             int* __restrict__ bsum, int n) {
    __shared__ int s[256];
    int tid = threadIdx.x;
    int i = blockIdx.x * 256 + tid;
    int v = (i < n) ? cnt_in[i] : 0;
    s[tid] = v;
    __syncthreads();
#pragma unroll
    for (int off = 1; off < 256; off <<= 1) {
        int t = (tid >= off) ? s[tid - off] : 0;
        __syncthreads();
        s[tid] += t;
        __syncthreads();
    }
    if (i < n) cursor[i] = s[tid] - v;
    if (tid == 255) bsum[blockIdx.x] = s[255];
}

__global__ void k_scan_bsum(int* __restrict__ bsum, int nb) {
    __shared__ int s[256];
    __shared__ int carry;
    int tid = threadIdx.x;
    if (tid == 0) carry = 0;
    __syncthreads();
    for (int start = 0; start < nb; start += 256) {
        int i = start + tid;
        int v = (i < nb) ? bsum[i] : 0;
        s[tid] = v;
        __syncthreads();
#pragma unroll
        for (int off = 1; off < 256; off <<= 1) {
            int t = (tid >= off) ? s[tid - off] : 0;
            __syncthreads();
            s[tid] += t;
            __syncthreads();
        }
        if (i < nb) bsum[i] = s[tid] - v + carry;
        __syncthreads();
        if (tid == 0) carry += s[255];
        __syncthreads();
    }
}

// one wave per node (4 nodes per 256-block); also produces xs = norm_src * x
__global__ void k_finalize_xs(const float* __restrict__ x,
                              const int* __restrict__ cnt_out, const int* __restrict__ cnt_in,
                              const int* __restrict__ bsum,
                              int* __restrict__ cursor,
                              float* __restrict__ norm_src, float* __restrict__ norm_dst,
                              float* __restrict__ xs, int n) {
    int idx = blockIdx.x * 256 + threadIdx.x;
    int node = idx >> 6;
    int d = idx & 63;
    if (node >= n) return;
    float ns = rsqrtf((float)(cnt_out[node] + 1));   // +1 self loop
    xs[(size_t)node * D + d] = ns * x[(size_t)node * D + d];
    if (d == 0) {
        cursor[node] += bsum[node >> 8];
        norm_src[node] = ns;
        norm_dst[node] = rsqrtf((float)(cnt_in[node] + 1));
    }
}

__global__ void k_bin(const int* __restrict__ src, const int* __restrict__ dst,
                      int* __restrict__ cursor, int* __restrict__ col, int e) {
    int i = blockIdx.x * blockDim.x + threadIdx.x;
    if (i < e) {
        int p = atomicAdd(&cursor[dst[i]], 1);
        col[p] = src[i];
    }
}

// one wave per node (grid-stride); W1 column + b1 + W2 register-resident;
// 4-way-split accumulator chains; cross-lane via v_readlane only
__global__ void __launch_bounds__(256) k_node(
        const float* __restrict__ xs,
        const int* __restrict__ cursor_end, const int* __restrict__ cnt_in,
        const int* __restrict__ col,
        const float* __restrict__ norm_src, const float* __restrict__ norm_dst,
        const float* __restrict__ W1, const float* __restrict__ b1,
        const float* __restrict__ W2,
        float* __restrict__ zs, int n) {
    int tid = threadIdx.x;
    int wave = tid >> 6;
    int lane = tid & 63;

    float w1[D];
#pragma unroll
    for (int k = 0; k < D; ++k) w1[k] = W1[k * D + lane];
    float b1v = b1[lane];
    float w2v = W2[lane];

    int nwaves = gridDim.x * 4;
    for (int node = blockIdx.x * 4 + wave; node < n; node += nwaves) {
        int cnt = cnt_in[node];
        int base = cursor_end[node] - cnt;

        float a0 = xs[(size_t)node * D + lane];  // self loop (pre-scaled)
        float a1 = 0.0f, a2 = 0.0f, a3 = 0.0f;

        for (int b0 = 0; b0 < cnt; b0 += 64) {
            int m = cnt - b0; if (m > 64) m = 64;
            int idx = (lane < m) ? col[base + b0 + lane] : 0;
            int j = 0;
            for (; j + 8 <= m; j += 8) {
                int s0 = rl_i(idx, j + 0), s1 = rl_i(idx, j + 1);
                int s2 = rl_i(idx, j + 2), s3 = rl_i(idx, j + 3);
                int s4 = rl_i(idx, j + 4), s5 = rl_i(idx, j + 5);
                int s6 = rl_i(idx, j + 6), s7 = rl_i(idx, j + 7);
                float x0 = xs[(size_t)s0 * D + lane];
                float x1 = xs[(size_t)s1 * D + lane];
                float x2 = xs[(size_t)s2 * D + lane];
                float x3 = xs[(size_t)s3 * D + lane];
                float x4 = xs[(size_t)s4 * D + lane];
                float x5 = xs[(size_t)s5 * D + lane];
                float x6 = xs[(size_t)s6 * D + lane];
                float x7 = xs[(size_t)s7 * D + lane];
                a0 += x0; a1 += x1; a2 += x2; a3 += x3;
                a0 += x4; a1 += x5; a2 += x6; a3 += x7;
            }
            for (; j < m; ++j)
                a0 += xs[(size_t)rl_i(idx, j) * D + lane];
        }
        float acc = ((a0 + a1) + (a2 + a3)) * norm_dst[node];

        // dense 64x64, W1 in registers, broadcast via readlane, ILP-4
        float h0 = b1v, h1 = 0.0f, h2 = 0.0f, h3 = 0.0f;
#pragma unroll
        for (int k = 0; k < D; k += 4) {
            h0 = fmaf(rl_f(acc, k + 0), w1[k + 0], h0);
            h1 = fmaf(rl_f(acc, k + 1), w1[k + 1], h1);
            h2 = fmaf(rl_f(acc, k + 2), w1[k + 2], h2);
            h3 = fmaf(rl_f(acc, k + 3), w1[k + 3], h3);
        }
        float h = fmaxf((h0 + h1) + (h2 + h3), 0.0f);

        float zp = h * w2v;
#pragma unroll
        for (int off = 32; off > 0; off >>= 1) zp += __shfl_down(zp, off);

        if (lane == 0) zs[node] = zp * norm_src[node];  // pre-scaled for layer 2
    }
}

// layer-2 gather: 8 lanes per node
__global__ void k_out(const float* __restrict__ zs,
                      const int* __restrict__ cursor_end, const int* __restrict__ cnt_in,
                      const int* __restrict__ col,
                      const float* __restrict__ norm_dst, const float* __restrict__ b2,
                      float* __restrict__ out, int n) {
    int g = blockIdx.x * blockDim.x + threadIdx.x;
    int node = g >> 3;
    int sub = g & 7;
    if (node >= n) return;
    int c = cnt_in[node];
    int base = cursor_end[node] - c;
    float s = (sub == 0) ? zs[node] : 0.0f;  // self loop
    for (int j = sub; j < c; j += 8) s += zs[col[base + j]];
    s += __shfl_xor(s, 1);
    s += __shfl_xor(s, 2);
    s += __shfl_xor(s, 4);
    if (sub == 0) out[node] = norm_dst[node] * s + b2[0];
}

extern "C" void kernel_launch(void* const* d_in, const int* in_sizes, int n_in,
                              void* d_out, int out_size, void* d_ws, size_t ws_size,
                              hipStream_t stream) {
    const float* x  = (const float*)d_in[0];
    const int*   ei = (const int*)d_in[1];
    const float* W1 = (const float*)d_in[2];
    const float* b1 = (const float*)d_in[3];
    const float* W2 = (const float*)d_in[4];
    const float* b2 = (const float*)d_in[5];
    float* out = (float*)d_out;

    const int n = in_sizes[0] / D;   // 50000
    const int e = in_sizes[1] / 2;   // 800000
    const int* src = ei;
    const int* dst = ei + e;

    const int nb = (n + 255) / 256;

    char* ws = (char*)d_ws;
    int*   cnt_out  = (int*)ws;   ws += sizeof(int) * (size_t)n;   // overlaid by zs later
    int*   cnt_in   = (int*)ws;   ws += sizeof(int) * (size_t)n;
    int*   cursor   = (int*)ws;   ws += sizeof(int) * (size_t)n;
    int*   bsum     = (int*)ws;   ws += sizeof(int) * (size_t)((nb + 255) & ~255);
    float* norm_src = (float*)ws; ws += sizeof(float) * (size_t)n;
    float* norm_dst = (float*)ws; ws += sizeof(float) * (size_t)n;
    int*   col      = (int*)ws;   ws += sizeof(int) * (size_t)e;
    float* xs       = (float*)ws; ws += sizeof(float) * (size_t)n * D;
    float* zs       = (float*)cnt_out;  // cnt_out dead after k_finalize_xs

    const int B = 256;

    hipMemsetAsync(cnt_out, 0, 2 * sizeof(int) * (size_t)n, stream);
    k_hist<<<(e + B - 1) / B, B, 0, stream>>>(src, dst, cnt_out, cnt_in, e);
    k_scan_block<<<nb, 256, 0, stream>>>(cnt_in, cursor, bsum, n);
    k_scan_bsum<<<1, 256, 0, stream>>>(bsum, nb);
    k_finalize_xs<<<((size_t)n * D + B - 1) / B, B, 0, stream>>>(
        x, cnt_out, cnt_in, bsum, cursor, norm_src, norm_dst, xs, n);
    k_bin<<<(e + B - 1) / B, B, 0, stream>>>(src, dst, cursor, col, e);
    k_node<<<2560, 256, 0, stream>>>(xs, cursor, cnt_in, col, norm_src, norm_dst,
                                     W1, b1, W2, zs, n);
    k_out<<<((size_t)n * 8 + B - 1) / B, B, 0, stream>>>(zs, cursor, cnt_in, col,
                                                         norm_dst, b2, out, n);
}

// Round 6
// 205.990 us; speedup vs baseline: 1.0378x; 1.0378x over previous
//
#include <hip/hip_runtime.h>

// GCN forward, f32, CSR-gather; W1 pinned in VGPRs via asm keepalive.
// Pipeline:
//  M  memsetAsync: zero cnt_out/cnt_in
//  K1 edge histogram (int atomics)
//  K2 per-block exclusive scan of cnt_in -> cursor(partial) + bsum
//  K3 single-block exclusive scan of bsum
//  K4 finalize: cursor += bsum-prefix; norm_src/norm_dst
//  K5 bin edges by dst (cursor -> end offsets)
//  K6 fused per-node (1 wave/node, grid-stride): gather + reg-MLP -> zs
//  K7 layer-2 gather (8 lanes/node) -> out
// zs overlays cnt_out (dead after K4).

constexpr int D = 64;

__device__ __forceinline__ int rl_i(int v, int l) {
    return __builtin_amdgcn_readlane(v, l);
}
__device__ __forceinline__ float rl_f(float v, int l) {
    return __builtin_bit_cast(float, __builtin_amdgcn_readlane(__builtin_bit_cast(int, v), l));
}

__global__ void k_hist(const int* __restrict__ src, const int* __restrict__ dst,
                       int* __restrict__ cnt_out, int* __restrict__ cnt_in, int e) {
    int i = blockIdx.x * blockDim.x + threadIdx.x;
    if (i < e) {
        atomicAdd(&cnt_out[src[i]], 1);
        atomicAdd(&cnt_in[dst[i]], 1);
    }
}

__global__ void k_scan_block(const int* __restrict__ cnt_in, int* __restrict__ cursor,
                             int* __restrict__ bsum, int n) {
    __shared__ int s[256];
    int tid = threadIdx.x;
    int i = blockIdx.x * 256 + tid;
    int v = (i < n) ? cnt_in[i] : 0;
    s[tid] = v;
    __syncthreads();
#pragma unroll
    for (int off = 1; off < 256; off <<= 1) {
        int t = (tid >= off) ? s[tid - off] : 0;
        __syncthreads();
        s[tid] += t;
        __syncthreads();
    }
    if (i < n) cursor[i] = s[tid] - v;
    if (tid == 255) bsum[blockIdx.x] = s[255];
}

__global__ void k_scan_bsum(int* __restrict__ bsum, int nb) {
    __shared__ int s[256];
    __shared__ int carry;
    int tid = threadIdx.x;
    if (tid == 0) carry = 0;
    __syncthreads();
    for (int start = 0; start < nb; start += 256) {
        int i = start + tid;
        int v = (i < nb) ? bsum[i] : 0;
        s[tid] = v;
        __syncthreads();
#pragma unroll
        for (int off = 1; off < 256; off <<= 1) {
            int t = (tid >= off) ? s[tid - off] : 0;
            __syncthreads();
            s[tid] += t;
            __syncthreads();
        }
        if (i < nb) bsum[i] = s[tid] - v + carry;
        __syncthreads();
        if (tid == 0) carry += s[255];
        __syncthreads();
    }
}

__global__ void k_finalize(const int* __restrict__ cnt_out, const int* __restrict__ cnt_in,
                           const int* __restrict__ bsum,
                           int* __restrict__ cursor,
                           float* __restrict__ norm_src, float* __restrict__ norm_dst, int n) {
    int i = blockIdx.x * blockDim.x + threadIdx.x;
    if (i >= n) return;
    cursor[i] += bsum[i >> 8];
    norm_src[i] = rsqrtf((float)(cnt_out[i] + 1));  // +1 self loop
    norm_dst[i] = rsqrtf((float)(cnt_in[i] + 1));
}

__global__ void k_bin(const int* __restrict__ src, const int* __restrict__ dst,
                      int* __restrict__ cursor, int* __restrict__ col, int e) {
    int i = blockIdx.x * blockDim.x + threadIdx.x;
    if (i < e) {
        int p = atomicAdd(&cursor[dst[i]], 1);
        col[p] = src[i];
    }
}

// one wave per node (grid-stride); W1 column + b1 + W2 PINNED in registers;
// cross-lane via v_readlane only (no LDS)
__global__ void __launch_bounds__(256) k_node(
        const float* __restrict__ x,
        const int* __restrict__ cursor_end, const int* __restrict__ cnt_in,
        const int* __restrict__ col,
        const float* __restrict__ norm_src, const float* __restrict__ norm_dst,
        const float* __restrict__ W1, const float* __restrict__ b1,
        const float* __restrict__ W2,
        float* __restrict__ zs, int n) {
    int tid = threadIdx.x;
    int wave = tid >> 6;
    int lane = tid & 63;

    float w1[D];
#pragma unroll
    for (int k = 0; k < D; ++k) w1[k] = W1[k * D + lane];
    float b1v = b1[lane];
    float w2v = W2[lane];
    // keepalive: make the asm the def of each w1[k] so the compiler cannot
    // sink/rematerialize the W1 loads into the per-node loop
#pragma unroll
    for (int k = 0; k < D; ++k) asm volatile("" : "+v"(w1[k]));
    asm volatile("" : "+v"(b1v), "+v"(w2v));

    const float* x_lane = x + lane;

    int nwaves = gridDim.x * 4;
    for (int node = blockIdx.x * 4 + wave; node < n; node += nwaves) {
        int cnt = cnt_in[node];
        int base = cursor_end[node] - cnt;

        float a0 = norm_src[node] * x_lane[(size_t)(node << 6)];  // self loop
        float a1 = 0.0f, a2 = 0.0f, a3 = 0.0f;

        for (int b0 = 0; b0 < cnt; b0 += 64) {
            int m = cnt - b0; if (m > 64) m = 64;
            int   idx = (lane < m) ? col[base + b0 + lane] : 0;
            float nsw = (lane < m) ? norm_src[idx] : 0.0f;
            int j = 0;
            for (; j + 8 <= m; j += 8) {
                int s0 = rl_i(idx, j + 0), s1 = rl_i(idx, j + 1);
                int s2 = rl_i(idx, j + 2), s3 = rl_i(idx, j + 3);
                int s4 = rl_i(idx, j + 4), s5 = rl_i(idx, j + 5);
                int s6 = rl_i(idx, j + 6), s7 = rl_i(idx, j + 7);
                float x0 = x_lane[(size_t)(s0 << 6)];
                float x1 = x_lane[(size_t)(s1 << 6)];
                float x2 = x_lane[(size_t)(s2 << 6)];
                float x3 = x_lane[(size_t)(s3 << 6)];
                float x4 = x_lane[(size_t)(s4 << 6)];
                float x5 = x_lane[(size_t)(s5 << 6)];
                float x6 = x_lane[(size_t)(s6 << 6)];
                float x7 = x_lane[(size_t)(s7 << 6)];
                a0 = fmaf(rl_f(nsw, j + 0), x0, a0);
                a1 = fmaf(rl_f(nsw, j + 1), x1, a1);
                a2 = fmaf(rl_f(nsw, j + 2), x2, a2);
                a3 = fmaf(rl_f(nsw, j + 3), x3, a3);
                a0 = fmaf(rl_f(nsw, j + 4), x4, a0);
                a1 = fmaf(rl_f(nsw, j + 5), x5, a1);
                a2 = fmaf(rl_f(nsw, j + 6), x6, a2);
                a3 = fmaf(rl_f(nsw, j + 7), x7, a3);
            }
            for (; j < m; ++j)
                a0 = fmaf(rl_f(nsw, j), x_lane[(size_t)(rl_i(idx, j) << 6)], a0);
        }
        float acc = ((a0 + a1) + (a2 + a3)) * norm_dst[node];

        // dense 64x64, W1 in registers, broadcast via readlane, ILP-4
        float h0 = b1v, h1 = 0.0f, h2 = 0.0f, h3 = 0.0f;
#pragma unroll
        for (int k = 0; k < D; k += 4) {
            h0 = fmaf(rl_f(acc, k + 0), w1[k + 0], h0);
            h1 = fmaf(rl_f(acc, k + 1), w1[k + 1], h1);
            h2 = fmaf(rl_f(acc, k + 2), w1[k + 2], h2);
            h3 = fmaf(rl_f(acc, k + 3), w1[k + 3], h3);
        }
        float h = fmaxf((h0 + h1) + (h2 + h3), 0.0f);

        float zp = h * w2v;
#pragma unroll
        for (int off = 32; off > 0; off >>= 1) zp += __shfl_down(zp, off);

        if (lane == 0) zs[node] = zp * norm_src[node];  // pre-scaled for layer 2
    }
}

// layer-2 gather: 8 lanes per node
__global__ void k_out(const float* __restrict__ zs,
                      const int* __restrict__ cursor_end, const int* __restrict__ cnt_in,
                      const int* __restrict__ col,
                      const float* __restrict__ norm_dst, const float* __restrict__ b2,
                      float* __restrict__ out, int n) {
    int g = blockIdx.x * blockDim.x + threadIdx.x;
    int node = g >> 3;
    int sub = g & 7;
    if (node >= n) return;
    int c = cnt_in[node];
    int base = cursor_end[node] - c;
    float s = (sub == 0) ? zs[node] : 0.0f;  // self loop
    for (int j = sub; j < c; j += 8) s += zs[col[base + j]];
    s += __shfl_xor(s, 1);
    s += __shfl_xor(s, 2);
    s += __shfl_xor(s, 4);
    if (sub == 0) out[node] = norm_dst[node] * s + b2[0];
}

extern "C" void kernel_launch(void* const* d_in, const int* in_sizes, int n_in,
                              void* d_out, int out_size, void* d_ws, size_t ws_size,
                              hipStream_t stream) {
    const float* x  = (const float*)d_in[0];
    const int*   ei = (const int*)d_in[1];
    const float* W1 = (const float*)d_in[2];
    const float* b1 = (const float*)d_in[3];
    const float* W2 = (const float*)d_in[4];
    const float* b2 = (const float*)d_in[5];
    float* out = (float*)d_out;

    const int n = in_sizes[0] / D;   // 50000
    const int e = in_sizes[1] / 2;   // 800000
    const int* src = ei;
    const int* dst = ei + e;

    const int nb = (n + 255) / 256;

    char* ws = (char*)d_ws;
    int*   cnt_out  = (int*)ws;   ws += sizeof(int) * (size_t)n;   // overlaid by zs later
    int*   cnt_in   = (int*)ws;   ws += sizeof(int) * (size_t)n;
    int*   cursor   = (int*)ws;   ws += sizeof(int) * (size_t)n;
    int*   bsum     = (int*)ws;   ws += sizeof(int) * (size_t)((nb + 255) & ~255);
    float* norm_src = (float*)ws; ws += sizeof(float) * (size_t)n;
    float* norm_dst = (float*)ws; ws += sizeof(float) * (size_t)n;
    int*   col      = (int*)ws;   ws += sizeof(int) * (size_t)e;
    float* zs       = (float*)cnt_out;  // cnt_out dead after k_finalize

    const int B = 256;

    hipMemsetAsync(cnt_out, 0, 2 * sizeof(int) * (size_t)n, stream);
    k_hist<<<(e + B - 1) / B, B, 0, stream>>>(src, dst, cnt_out, cnt_in, e);
    k_scan_block<<<nb, 256, 0, stream>>>(cnt_in, cursor, bsum, n);
    k_scan_bsum<<<1, 256, 0, stream>>>(bsum, nb);
    k_finalize<<<(n + B - 1) / B, B, 0, stream>>>(cnt_out, cnt_in, bsum, cursor,
                                                  norm_src, norm_dst, n);
    k_bin<<<(e + B - 1) / B, B, 0, stream>>>(src, dst, cursor, col, e);
    k_node<<<2560, 256, 0, stream>>>(x, cursor, cnt_in, col, norm_src, norm_dst,
                                     W1, b1, W2, zs, n);
    k_out<<<((size_t)n * 8 + B - 1) / B, B, 0, stream>>>(zs, cursor, cnt_in, col,
                                                         norm_dst, b2, out, n);
}

// Round 7
// 202.943 us; speedup vs baseline: 1.0534x; 1.0150x over previous
//
#include <hip/hip_runtime.h>

// GCN forward, f32. Key identity: aggregate(x) @ W1 == aggregate(x @ W1)
// (aggregation = diagonal scaling + row sums, commutes with right-mult).
// Pipeline:
//  M   memsetAsync: zero cnt_out/cnt_in
//  K1  edge histogram (int atomics)
//  K2  per-block exclusive scan of cnt_in -> cursor(partial) + bsum
//  K3  single-block exclusive scan of bsum
//  K4  finalize: cursor=start; meta[i]=(start,cnt_in,cnt_out,0)
//  K5  bin edges by dst: col2[p] = (src, norm_src[src])
//  K6  gemm: y = x @ W1  (8 rows/wave, W1 column load amortized 8x)
//  K7  per-node (1 wave/node): gather y via col2 -> +b1,relu,dot W2 -> zs
//  K8  layer-2 gather (8 lanes/node) -> out

constexpr int D = 64;

__device__ __forceinline__ int rl_i(int v, int l) { return __builtin_amdgcn_readlane(v, l); }
__device__ __forceinline__ float rl_f(float v, int l) {
    return __builtin_bit_cast(float, __builtin_amdgcn_readlane(__builtin_bit_cast(int, v), l));
}

__global__ void k_hist(const int* __restrict__ src, const int* __restrict__ dst,
                       int* __restrict__ cnt_out, int* __restrict__ cnt_in, int e) {
    int i = blockIdx.x * blockDim.x + threadIdx.x;
    if (i < e) {
        atomicAdd(&cnt_out[src[i]], 1);
        atomicAdd(&cnt_in[dst[i]], 1);
    }
}

__global__ void k_scan_block(const int* __restrict__ cnt_in, int* __restrict__ cursor,
                             int* __restrict__ bsum, int n) {
    __shared__ int s[256];
    int tid = threadIdx.x;
    int i = blockIdx.x * 256 + tid;
    int v = (i < n) ? cnt_in[i] : 0;
    s[tid] = v;
    __syncthreads();
#pragma unroll
    for (int off = 1; off < 256; off <<= 1) {
        int t = (tid >= off) ? s[tid - off] : 0;
        __syncthreads();
        s[tid] += t;
        __syncthreads();
    }
    if (i < n) cursor[i] = s[tid] - v;
    if (tid == 255) bsum[blockIdx.x] = s[255];
}

__global__ void k_scan_bsum(int* __restrict__ bsum, int nb) {
    __shared__ int s[256];
    __shared__ int carry;
    int tid = threadIdx.x;
    if (tid == 0) carry = 0;
    __syncthreads();
    for (int start = 0; start < nb; start += 256) {
        int i = start + tid;
        int v = (i < nb) ? bsum[i] : 0;
        s[tid] = v;
        __syncthreads();
#pragma unroll
        for (int off = 1; off < 256; off <<= 1) {
            int t = (tid >= off) ? s[tid - off] : 0;
            __syncthreads();
            s[tid] += t;
            __syncthreads();
        }
        if (i < nb) bsum[i] = s[tid] - v + carry;
        __syncthreads();
        if (tid == 0) carry += s[255];
        __syncthreads();
    }
}

__global__ void k_finalize(const int* __restrict__ cnt_out, const int* __restrict__ cnt_in,
                           const int* __restrict__ bsum,
                           int* __restrict__ cursor, int4* __restrict__ meta, int n) {
    int i = blockIdx.x * blockDim.x + threadIdx.x;
    if (i >= n) return;
    int start = cursor[i] + bsum[i >> 8];
    cursor[i] = start;
    meta[i] = make_int4(start, cnt_in[i], cnt_out[i], 0);
}

__global__ void k_bin(const int* __restrict__ src, const int* __restrict__ dst,
                      const int* __restrict__ cnt_out,
                      int* __restrict__ cursor, int2* __restrict__ col2, int e) {
    int i = blockIdx.x * blockDim.x + threadIdx.x;
    if (i < e) {
        int s = src[i];
        int p = atomicAdd(&cursor[dst[i]], 1);
        float w = rsqrtf((float)(cnt_out[s] + 1));   // norm_src[s], +1 self loop
        col2[p] = make_int2(s, __builtin_bit_cast(int, w));
    }
}

// y = x @ W1: one wave handles 8 rows; lane = output column.
// W1[k][lane] loaded once per k and shared across the 8 rows (8x amortized).
__global__ void __launch_bounds__(256) k_gemm(
        const float* __restrict__ x, const float* __restrict__ W1,
        float* __restrict__ y, int n) {
    int tid = threadIdx.x;
    int wave = tid >> 6;
    int lane = tid & 63;
    int gwave = blockIdx.x * 4 + wave;
    int r0 = gwave * 8;
    if (r0 >= n) return;

    float xr[8], acc[8];
#pragma unroll
    for (int i = 0; i < 8; ++i) {
        int r = r0 + i;
        xr[i] = (r < n) ? x[(size_t)r * D + lane] : 0.0f;
        acc[i] = 0.0f;
    }
#pragma unroll
    for (int k = 0; k < D; ++k) {
        float wk = W1[k * D + lane];
#pragma unroll
        for (int i = 0; i < 8; ++i)
            acc[i] = fmaf(rl_f(xr[i], k), wk, acc[i]);
    }
#pragma unroll
    for (int i = 0; i < 8; ++i) {
        int r = r0 + i;
        if (r < n) y[(size_t)r * D + lane] = acc[i];
    }
}

// one wave per node (grid-stride, all-resident grid); all loads coalesced.
__global__ void __launch_bounds__(256) k_node(
        const float* __restrict__ y, const int4* __restrict__ meta,
        const int2* __restrict__ col2,
        const float* __restrict__ b1, const float* __restrict__ W2,
        float* __restrict__ zs, int n) {
    int tid = threadIdx.x;
    int wave = tid >> 6;
    int lane = tid & 63;
    float b1v = b1[lane];
    float w2v = W2[lane];

    int nwaves = gridDim.x * 4;
    int node = blockIdx.x * 4 + wave;
    if (node >= n) return;
    int4 mt = meta[node];

    while (true) {
        int nxt = node + nwaves;
        int4 mt_nx = make_int4(0, 0, 0, 0);
        if (nxt < n) mt_nx = meta[nxt];          // prefetch next node's meta

        int base = mt.x;
        int cnt = mt.y;
        float nd = rsqrtf((float)(mt.y + 1));    // norm_dst
        float ns = rsqrtf((float)(mt.z + 1));    // norm_src

        float a0 = ns * y[(size_t)node * D + lane];  // self loop
        float a1 = 0.0f, a2 = 0.0f, a3 = 0.0f;

        for (int b0 = 0; b0 < cnt; b0 += 64) {
            int m = cnt - b0; if (m > 64) m = 64;
            int2 cw = (lane < m) ? col2[base + b0 + lane] : make_int2(0, 0);
            int idx = cw.x;
            float w = __builtin_bit_cast(float, cw.y);
            int j = 0;
            for (; j + 8 <= m; j += 8) {
                int s0 = rl_i(idx, j + 0), s1 = rl_i(idx, j + 1);
                int s2 = rl_i(idx, j + 2), s3 = rl_i(idx, j + 3);
                int s4 = rl_i(idx, j + 4), s5 = rl_i(idx, j + 5);
                int s6 = rl_i(idx, j + 6), s7 = rl_i(idx, j + 7);
                float x0 = y[(size_t)s0 * D + lane];
                float x1 = y[(size_t)s1 * D + lane];
                float x2 = y[(size_t)s2 * D + lane];
                float x3 = y[(size_t)s3 * D + lane];
                float x4 = y[(size_t)s4 * D + lane];
                float x5 = y[(size_t)s5 * D + lane];
                float x6 = y[(size_t)s6 * D + lane];
                float x7 = y[(size_t)s7 * D + lane];
                a0 = fmaf(rl_f(w, j + 0), x0, a0);
                a1 = fmaf(rl_f(w, j + 1), x1, a1);
                a2 = fmaf(rl_f(w, j + 2), x2, a2);
                a3 = fmaf(rl_f(w, j + 3), x3, a3);
                a0 = fmaf(rl_f(w, j + 4), x4, a0);
                a1 = fmaf(rl_f(w, j + 5), x5, a1);
                a2 = fmaf(rl_f(w, j + 6), x6, a2);
                a3 = fmaf(rl_f(w, j + 7), x7, a3);
            }
            for (; j < m; ++j)
                a0 = fmaf(rl_f(w, j), y[(size_t)rl_i(idx, j) * D + lane], a0);
        }

        float h = fmaxf(((a0 + a1) + (a2 + a3)) * nd + b1v, 0.0f);
        float zp = h * w2v;
#pragma unroll
        for (int off = 32; off > 0; off >>= 1) zp += __shfl_down(zp, off);
        if (lane == 0) zs[node] = zp * ns;       // pre-scaled for layer 2

        if (nxt >= n) break;
        node = nxt;
        mt = mt_nx;
    }
}

// layer-2 gather: 8 lanes per node
__global__ void k_out(const float* __restrict__ zs,
                      const int4* __restrict__ meta, const int2* __restrict__ col2,
                      const float* __restrict__ b2,
                      float* __restrict__ out, int n) {
    int g = blockIdx.x * blockDim.x + threadIdx.x;
    int node = g >> 3;
    int sub = g & 7;
    if (node >= n) return;
    int4 mt = meta[node];
    int base = mt.x;
    int c = mt.y;
    float s = (sub == 0) ? zs[node] : 0.0f;   // self loop (zs pre-scaled)
    for (int j = sub; j < c; j += 8) s += zs[col2[base + j].x];
    s += __shfl_xor(s, 1);
    s += __shfl_xor(s, 2);
    s += __shfl_xor(s, 4);
    if (sub == 0) {
        float nd = rsqrtf((float)(mt.y + 1));
        out[node] = nd * s + b2[0];
    }
}

extern "C" void kernel_launch(void* const* d_in, const int* in_sizes, int n_in,
                              void* d_out, int out_size, void* d_ws, size_t ws_size,
                              hipStream_t stream) {
    const float* x  = (const float*)d_in[0];
    const int*   ei = (const int*)d_in[1];
    const float* W1 = (const float*)d_in[2];
    const float* b1 = (const float*)d_in[3];
    const float* W2 = (const float*)d_in[4];
    const float* b2 = (const float*)d_in[5];
    float* out = (float*)d_out;

    const int n = in_sizes[0] / D;   // 50000
    const int e = in_sizes[1] / 2;   // 800000
    const int* src = ei;
    const int* dst = ei + e;

    const int nb = (n + 255) / 256;

    char* ws = (char*)d_ws;
    int*   cnt_out = (int*)ws;   ws += sizeof(int) * (size_t)n;
    int*   cnt_in  = (int*)ws;   ws += sizeof(int) * (size_t)n;   // overlaid by zs after finalize
    int*   cursor  = (int*)ws;   ws += sizeof(int) * (size_t)n;
    int*   bsum    = (int*)ws;   ws += sizeof(int) * (size_t)((nb + 255) & ~255);
    int4*  meta    = (int4*)ws;  ws += sizeof(int4) * (size_t)n;
    int2*  col2    = (int2*)ws;  ws += sizeof(int2) * (size_t)e;
    float* y       = (float*)ws; ws += sizeof(float) * (size_t)n * D;
    float* zs      = (float*)cnt_in;  // cnt_in dead after k_finalize

    const int B = 256;

    hipMemsetAsync(cnt_out, 0, 2 * sizeof(int) * (size_t)n, stream);
    k_hist<<<(e + B - 1) / B, B, 0, stream>>>(src, dst, cnt_out, cnt_in, e);
    k_scan_block<<<nb, 256, 0, stream>>>(cnt_in, cursor, bsum, n);
    k_scan_bsum<<<1, 256, 0, stream>>>(bsum, nb);
    k_finalize<<<(n + B - 1) / B, B, 0, stream>>>(cnt_out, cnt_in, bsum, cursor, meta, n);
    k_bin<<<(e + B - 1) / B, B, 0, stream>>>(src, dst, cnt_out, cursor, col2, e);
    k_gemm<<<(n + 31) / 32, B, 0, stream>>>(x, W1, y, n);
    k_node<<<2048, B, 0, stream>>>(y, meta, col2, b1, W2, zs, n);
    k_out<<<((size_t)n * 8 + B - 1) / B, B, 0, stream>>>(zs, meta, col2, b2, out, n);
}

// Round 8
// 124.365 us; speedup vs baseline: 1.7189x; 1.6318x over previous
//
#include <hip/hip_runtime.h>

// GCN forward, f32. aggregate(x)@W1 == aggregate(x@W1); CSR build via
// LDS-local counting sort (no memory-side atomics).
// Pipeline:
//  K1 k_hist_lds : 64 chunks x 4 node-passes, packed LDS histogram -> part[]
//  K2 k_merge    : sum partials -> cnt_out/cnt_in; colpref[b][v] (ushort)
//  K3 k_scan_block / K4 k_scan_bsum : exclusive scan of cnt_in
//  K5 k_finalize : row_start; meta[v]=(start,cnt_in,cnt_out,0)
//  K6 k_bin_lds  : LDS cursor = start+colpref; col2[p]=(src, norm_src[src])
//  K7 k_gemm     : y = x @ W1   (8 rows/wave, W1 col amortized 8x)
//  K8 k_node     : per-node gather of y -> +b1, relu, dot W2 -> zs
//  K9 k_out      : layer-2 scalar gather -> out
// y overlays part (dead after k_merge); zs overlays cnt_in (dead after K5).

constexpr int D = 64;
constexpr int NODE_TILE = 12800;   // LDS counters per pass (50 KB)
constexpr int NCHUNK = 64;         // edge chunks
constexpr int HTH = 1024;          // threads for hist/bin blocks

__device__ __forceinline__ int rl_i(int v, int l) { return __builtin_amdgcn_readlane(v, l); }
__device__ __forceinline__ float rl_f(float v, int l) {
    return __builtin_bit_cast(float, __builtin_amdgcn_readlane(__builtin_bit_cast(int, v), l));
}

// packed LDS histogram: low 16 bits = out-degree (src), high 16 = in-degree (dst)
__global__ void __launch_bounds__(HTH) k_hist_lds(
        const int* __restrict__ src, const int* __restrict__ dst,
        unsigned int* __restrict__ part, int e, int ce) {
    __shared__ unsigned int h[NODE_TILE];
    int b = blockIdx.x;
    int v0 = blockIdx.y * NODE_TILE;
    for (int i = threadIdx.x; i < NODE_TILE; i += HTH) h[i] = 0u;
    __syncthreads();
    int lo = b * ce, hi = min(lo + ce, e);
    for (int i = lo + threadIdx.x; i < hi; i += HTH) {
        unsigned int us = (unsigned int)(src[i] - v0);
        if (us < (unsigned int)NODE_TILE) atomicAdd(&h[us], 1u);
        unsigned int ud = (unsigned int)(dst[i] - v0);
        if (ud < (unsigned int)NODE_TILE) atomicAdd(&h[ud], 0x10000u);
    }
    __syncthreads();
    unsigned int* p = part + ((size_t)blockIdx.y * NCHUNK + b) * NODE_TILE;
    for (int i = threadIdx.x; i < NODE_TILE; i += HTH) p[i] = h[i];
}

// per node: sum 64 partials -> counts; exclusive prefix of in-counts -> colpref
__global__ void k_merge(const unsigned int* __restrict__ part,
                        unsigned short* __restrict__ colpref,
                        int* __restrict__ cnt_out, int* __restrict__ cnt_in, int n) {
    int v = blockIdx.x * blockDim.x + threadIdx.x;
    if (v >= n) return;
    int pass = v / NODE_TILE;
    int vl = v - pass * NODE_TILE;
    const unsigned int* p = part + (size_t)pass * NCHUNK * NODE_TILE + vl;
    unsigned int tot = 0, run_in = 0;
    for (int b = 0; b < NCHUNK; ++b) {
        colpref[(size_t)b * n + v] = (unsigned short)run_in;
        unsigned int t = p[(size_t)b * NODE_TILE];
        tot += t;
        run_in += t >> 16;
    }
    cnt_out[v] = (int)(tot & 0xFFFFu);
    cnt_in[v] = (int)(tot >> 16);
}

__global__ void k_scan_block(const int* __restrict__ cnt_in, int* __restrict__ cursor,
                             int* __restrict__ bsum, int n) {
    __shared__ int s[256];
    int tid = threadIdx.x;
    int i = blockIdx.x * 256 + tid;
    int v = (i < n) ? cnt_in[i] : 0;
    s[tid] = v;
    __syncthreads();
#pragma unroll
    for (int off = 1; off < 256; off <<= 1) {
        int t = (tid >= off) ? s[tid - off] : 0;
        __syncthreads();
        s[tid] += t;
        __syncthreads();
    }
    if (i < n) cursor[i] = s[tid] - v;
    if (tid == 255) bsum[blockIdx.x] = s[255];
}

__global__ void k_scan_bsum(int* __restrict__ bsum, int nb) {
    __shared__ int s[256];
    __shared__ int carry;
    int tid = threadIdx.x;
    if (tid == 0) carry = 0;
    __syncthreads();
    for (int start = 0; start < nb; start += 256) {
        int i = start + tid;
        int v = (i < nb) ? bsum[i] : 0;
        s[tid] = v;
        __syncthreads();
#pragma unroll
        for (int off = 1; off < 256; off <<= 1) {
            int t = (tid >= off) ? s[tid - off] : 0;
            __syncthreads();
            s[tid] += t;
            __syncthreads();
        }
        if (i < nb) bsum[i] = s[tid] - v + carry;
        __syncthreads();
        if (tid == 0) carry += s[255];
        __syncthreads();
    }
}

__global__ void k_finalize(const int* __restrict__ cnt_out, const int* __restrict__ cnt_in,
                           const int* __restrict__ bsum,
                           int* __restrict__ cursor, int4* __restrict__ meta, int n) {
    int i = blockIdx.x * blockDim.x + threadIdx.x;
    if (i >= n) return;
    int start = cursor[i] + bsum[i >> 8];
    cursor[i] = start;
    meta[i] = make_int4(start, cnt_in[i], cnt_out[i], 0);
}

// bin via LDS cursor (fast LDS atomics); only col2 store goes to memory
__global__ void __launch_bounds__(HTH) k_bin_lds(
        const int* __restrict__ src, const int* __restrict__ dst,
        const int* __restrict__ start, const unsigned short* __restrict__ colpref,
        const int* __restrict__ cnt_out,
        int2* __restrict__ col2, int e, int n, int ce) {
    __shared__ int cur[NODE_TILE];
    int b = blockIdx.x;
    int v0 = blockIdx.y * NODE_TILE;
    int vcnt = min(NODE_TILE, n - v0);
    for (int i = threadIdx.x; i < vcnt; i += HTH)
        cur[i] = start[v0 + i] + (int)colpref[(size_t)b * n + v0 + i];
    __syncthreads();
    int lo = b * ce, hi = min(lo + ce, e);
    for (int i = lo + threadIdx.x; i < hi; i += HTH) {
        int d = dst[i];
        unsigned int ud = (unsigned int)(d - v0);
        if (ud < (unsigned int)NODE_TILE) {
            int s = src[i];
            int p = atomicAdd(&cur[ud], 1);
            float w = rsqrtf((float)(cnt_out[s] + 1));  // norm_src[s]
            col2[p] = make_int2(s, __builtin_bit_cast(int, w));
        }
    }
}

// y = x @ W1: one wave handles 8 rows; lane = output column.
__global__ void __launch_bounds__(256) k_gemm(
        const float* __restrict__ x, const float* __restrict__ W1,
        float* __restrict__ y, int n) {
    int tid = threadIdx.x;
    int wave = tid >> 6;
    int lane = tid & 63;
    int r0 = (blockIdx.x * 4 + wave) * 8;
    if (r0 >= n) return;

    float xr[8], acc[8];
#pragma unroll
    for (int i = 0; i < 8; ++i) {
        int r = r0 + i;
        xr[i] = (r < n) ? x[(size_t)r * D + lane] : 0.0f;
        acc[i] = 0.0f;
    }
#pragma unroll
    for (int k = 0; k < D; ++k) {
        float wk = W1[k * D + lane];
#pragma unroll
        for (int i = 0; i < 8; ++i)
            acc[i] = fmaf(rl_f(xr[i], k), wk, acc[i]);
    }
#pragma unroll
    for (int i = 0; i < 8; ++i) {
        int r = r0 + i;
        if (r < n) y[(size_t)r * D + lane] = acc[i];
    }
}

// one wave per node (grid-stride); all loads coalesced
__global__ void __launch_bounds__(256) k_node(
        const float* __restrict__ y, const int4* __restrict__ meta,
        const int2* __restrict__ col2,
        const float* __restrict__ b1, const float* __restrict__ W2,
        float* __restrict__ zs, int n) {
    int tid = threadIdx.x;
    int wave = tid >> 6;
    int lane = tid & 63;
    float b1v = b1[lane];
    float w2v = W2[lane];

    int nwaves = gridDim.x * 4;
    int node = blockIdx.x * 4 + wave;
    if (node >= n) return;
    int4 mt = meta[node];

    while (true) {
        int nxt = node + nwaves;
        int4 mt_nx = make_int4(0, 0, 0, 0);
        if (nxt < n) mt_nx = meta[nxt];          // prefetch next node's meta

        int base = mt.x;
        int cnt = mt.y;
        float nd = rsqrtf((float)(mt.y + 1));    // norm_dst
        float ns = rsqrtf((float)(mt.z + 1));    // norm_src

        float a0 = ns * y[(size_t)node * D + lane];  // self loop
        float a1 = 0.0f, a2 = 0.0f, a3 = 0.0f;

        for (int b0 = 0; b0 < cnt; b0 += 64) {
            int m = cnt - b0; if (m > 64) m = 64;
            int2 cw = (lane < m) ? col2[base + b0 + lane] : make_int2(0, 0);
            int idx = cw.x;
            float w = __builtin_bit_cast(float, cw.y);
            int j = 0;
            for (; j + 8 <= m; j += 8) {
                int s0 = rl_i(idx, j + 0), s1 = rl_i(idx, j + 1);
                int s2 = rl_i(idx, j + 2), s3 = rl_i(idx, j + 3);
                int s4 = rl_i(idx, j + 4), s5 = rl_i(idx, j + 5);
                int s6 = rl_i(idx, j + 6), s7 = rl_i(idx, j + 7);
                float x0 = y[(size_t)s0 * D + lane];
                float x1 = y[(size_t)s1 * D + lane];
                float x2 = y[(size_t)s2 * D + lane];
                float x3 = y[(size_t)s3 * D + lane];
                float x4 = y[(size_t)s4 * D + lane];
                float x5 = y[(size_t)s5 * D + lane];
                float x6 = y[(size_t)s6 * D + lane];
                float x7 = y[(size_t)s7 * D + lane];
                a0 = fmaf(rl_f(w, j + 0), x0, a0);
                a1 = fmaf(rl_f(w, j + 1), x1, a1);
                a2 = fmaf(rl_f(w, j + 2), x2, a2);
                a3 = fmaf(rl_f(w, j + 3), x3, a3);
                a0 = fmaf(rl_f(w, j + 4), x4, a0);
                a1 = fmaf(rl_f(w, j + 5), x5, a1);
                a2 = fmaf(rl_f(w, j + 6), x6, a2);
                a3 = fmaf(rl_f(w, j + 7), x7, a3);
            }
            for (; j < m; ++j)
                a0 = fmaf(rl_f(w, j), y[(size_t)rl_i(idx, j) * D + lane], a0);
        }

        float h = fmaxf(((a0 + a1) + (a2 + a3)) * nd + b1v, 0.0f);
        float zp = h * w2v;
#pragma unroll
        for (int off = 32; off > 0; off >>= 1) zp += __shfl_down(zp, off);
        if (lane == 0) zs[node] = zp * ns;       // pre-scaled for layer 2

        if (nxt >= n) break;
        node = nxt;
        mt = mt_nx;
    }
}

// layer-2 gather: 8 lanes per node
__global__ void k_out(const float* __restrict__ zs,
                      const int4* __restrict__ meta, const int2* __restrict__ col2,
                      const float* __restrict__ b2,
                      float* __restrict__ out, int n) {
    int g = blockIdx.x * blockDim.x + threadIdx.x;
    int node = g >> 3;
    int sub = g & 7;
    if (node >= n) return;
    int4 mt = meta[node];
    int base = mt.x;
    int c = mt.y;
    float s = (sub == 0) ? zs[node] : 0.0f;   // self loop (zs pre-scaled)
    for (int j = sub; j < c; j += 8) s += zs[col2[base + j].x];
    s += __shfl_xor(s, 1);
    s += __shfl_xor(s, 2);
    s += __shfl_xor(s, 4);
    if (sub == 0) {
        float nd = rsqrtf((float)(mt.y + 1));
        out[node] = nd * s + b2[0];
    }
}

extern "C" void kernel_launch(void* const* d_in, const int* in_sizes, int n_in,
                              void* d_out, int out_size, void* d_ws, size_t ws_size,
                              hipStream_t stream) {
    const float* x  = (const float*)d_in[0];
    const int*   ei = (const int*)d_in[1];
    const float* W1 = (const float*)d_in[2];
    const float* b1 = (const float*)d_in[3];
    const float* W2 = (const float*)d_in[4];
    const float* b2 = (const float*)d_in[5];
    float* out = (float*)d_out;

    const int n = in_sizes[0] / D;   // 50000
    const int e = in_sizes[1] / 2;   // 800000
    const int* src = ei;
    const int* dst = ei + e;

    const int nb = (n + 255) / 256;
    const int npass = (n + NODE_TILE - 1) / NODE_TILE;      // 4
    const int ce = (e + NCHUNK - 1) / NCHUNK;               // 12500

    // workspace layout
    char* ws = (char*)d_ws;
    int*   cnt_out = (int*)ws;   ws += sizeof(int) * (size_t)n;
    int*   cnt_in  = (int*)ws;   ws += sizeof(int) * (size_t)n;   // zs overlays after finalize
    int*   cursor  = (int*)ws;   ws += sizeof(int) * (size_t)n;
    int*   bsum    = (int*)ws;   ws += sizeof(int) * (size_t)((nb + 255) & ~255);
    int4*  meta    = (int4*)ws;  ws += sizeof(int4) * (size_t)n;
    unsigned short* colpref = (unsigned short*)ws;
    ws += sizeof(unsigned short) * (size_t)NCHUNK * n;
    int2*  col2    = (int2*)ws;  ws += sizeof(int2) * (size_t)e;
    size_t part_bytes = sizeof(unsigned int) * (size_t)npass * NCHUNK * NODE_TILE;
    size_t y_bytes    = sizeof(float) * (size_t)n * D;
    unsigned int* part = (unsigned int*)ws;
    float* y = (float*)ws;       // y overlays part (part dead after k_merge)
    ws += (part_bytes > y_bytes ? part_bytes : y_bytes);
    float* zs = (float*)cnt_in;  // cnt_in dead after k_finalize

    const int B = 256;

    k_hist_lds<<<dim3(NCHUNK, npass), HTH, 0, stream>>>(src, dst, part, e, ce);
    k_merge<<<(n + B - 1) / B, B, 0, stream>>>(part, colpref, cnt_out, cnt_in, n);
    k_scan_block<<<nb, 256, 0, stream>>>(cnt_in, cursor, bsum, n);
    k_scan_bsum<<<1, 256, 0, stream>>>(bsum, nb);
    k_finalize<<<(n + B - 1) / B, B, 0, stream>>>(cnt_out, cnt_in, bsum, cursor, meta, n);
    k_bin_lds<<<dim3(NCHUNK, npass), HTH, 0, stream>>>(src, dst, cursor, colpref,
                                                       cnt_out, col2, e, n, ce);
    k_gemm<<<(n + 31) / 32, B, 0, stream>>>(x, W1, y, n);
    k_node<<<2048, B, 0, stream>>>(y, meta, col2, b1, W2, zs, n);
    k_out<<<((size_t)n * 8 + B - 1) / B, B, 0, stream>>>(zs, meta, col2, b2, out, n);
}